// Round 7
// baseline (786.405 us; speedup 1.0000x reference)
//
#include <hip/hip_runtime.h>

// PGWCrossAttention on MI355X (gfx950), bf16 MFMA pipeline.
// R11: FLASH-STYLE FUSION softmax+PV+concat -> k_pvf. After 5 null rounds of
// GEMM-structure work, the profile (no kernel >76us since R6) says time is a
// SUM of near-floor passes; the lever is pass elimination. k_pvf streams sd+pi
// once, computes e in-reg, stages e-tiles in swizzled dbuf LDS (T2: 128B-stride
// b128 A-reads are 16-way conflicted unswizzled), MFMAs vs L2-resident VT,
// keeps rowsum block-local (block spans all M), writes [cs|ce|cs-ce|cs*ce]
// directly. Kills attn (67MB w + 67MB r), ctx round-trip (34MB), rowsum
// round-trip, 7 launches. Chunks now 4 batches (sd 67MB = old attn slot).
#define Bsz 8
#define Nq  2048
#define Mk  2048
#define BKt 32          // K-tile per MFMA step
#define BUFE (128 * BKt) // elements per LDS buffer

typedef __attribute__((ext_vector_type(8))) short   short8;   // 8 bf16 (4 VGPRs)
typedef __attribute__((ext_vector_type(4))) float   floatx4;  // MFMA acc

__device__ __forceinline__ unsigned short f2bf(float f) {
  union { float f; unsigned u; } x; x.f = f;
  unsigned r = x.u + 0x7fffu + ((x.u >> 16) & 1u);   // RNE
  return (unsigned short)(r >> 16);
}
__device__ __forceinline__ float bf2f(unsigned short s) {
  union { unsigned u; float f; } x; x.u = ((unsigned)s) << 16;
  return x.f;
}

// async global->LDS, 16B per lane. LDS dest is wave-uniform base + lane*16.
__device__ __forceinline__ void gload16(const unsigned short* g, unsigned short* l) {
  __builtin_amdgcn_global_load_lds(
      (const __attribute__((address_space(1))) void*)g,
      (__attribute__((address_space(3))) void*)l, 16, 0, 0);
}

// ---------------------------------------------------------------------------
// 8-wave NT GEMM core 128x128, double-buffered: C += A[128,K] . B[128,K]^T.
// 512 threads, waves 2x4, wave tile 64x32, acc[4][2].
// ---------------------------------------------------------------------------
__device__ __forceinline__ void gemm_core8_nt(
    const unsigned short* __restrict__ A, int lda,
    const unsigned short* __restrict__ B, int ldb,
    int K, unsigned short* ldsA, unsigned short* ldsB,
    floatx4 (&acc)[4][2])
{
  const int tid  = threadIdx.x;
  const int lane = tid & 63;
  const int wid  = tid >> 6;          // 0..7
  const int wm   = wid & 1;
  const int wn   = wid >> 1;          // 0..3
  const int fr   = lane & 15;
  const int fk   = (lane >> 4) << 3;
  const int lr   = lane >> 2;         // 0..15
  const int lc   = (lane & 3) << 3;   // 0/8/16/24
  const int r0   = wid << 4;          // 16 rows per wave

  const unsigned short* gA = A + (size_t)(r0 + lr) * lda + lc;
  const unsigned short* gB = B + (size_t)(r0 + lr) * ldb + lc;
  unsigned short* lA = ldsA + r0 * BKt;
  unsigned short* lB = ldsB + r0 * BKt;
  const unsigned short* fa = ldsA + (wm * 64 + fr) * BKt + fk;
  const unsigned short* fb = ldsB + (wn * 32 + fr) * BKt + fk;

  // prologue: stage K-step 0 into buffer 0
  gload16(gA, lA); gA += BKt;
  gload16(gB, lB); gB += BKt;
  __syncthreads();

  int cur = 0;
  for (int k0 = 0; k0 < K; k0 += BKt) {
    const int nxt = cur ^ 1;
    if (k0 + BKt < K) {               // issue next-tile prefetch (async)
      gload16(gA, lA + nxt * BUFE); gA += BKt;
      gload16(gB, lB + nxt * BUFE); gB += BKt;
    }
    const unsigned short* fac = fa + cur * BUFE;
    const unsigned short* fbc = fb + cur * BUFE;
    short8 af[4], bfr[2];
#pragma unroll
    for (int i = 0; i < 4; i++) af[i]  = *(const short8*)(fac + i * 16 * BKt);
#pragma unroll
    for (int j = 0; j < 2; j++) bfr[j] = *(const short8*)(fbc + j * 16 * BKt);
#pragma unroll
    for (int i = 0; i < 4; i++)
#pragma unroll
      for (int j = 0; j < 2; j++)
        acc[i][j] = __builtin_amdgcn_mfma_f32_16x16x32_bf16(af[i], bfr[j], acc[i][j], 0, 0, 0);
    __syncthreads();                  // drains prefetch; buf safe to overwrite
    cur = nxt;
  }
}

#define EPILOGUE_VARS \
  const int lane = threadIdx.x & 63; \
  const int wid  = threadIdx.x >> 6; \
  const int wm   = wid & 1; \
  const int wn   = wid >> 1; \
  const int r4   = (lane >> 4) * 4;  \
  const int cn   = lane & 15; \
  (void)wid;

// ---------------------------------------------------------------------------
// Projection GEMM, A in fp32 (bf16-cast in regs, issue-early/write-late).
// B (bf16 weights) staged via global_load_lds. 128x128 tile, 8 waves, dbuf.
// ---------------------------------------------------------------------------
__global__ __launch_bounds__(512, 4) void k_proj(
    const float* __restrict__ A, const unsigned short* __restrict__ Bw,
    const float* __restrict__ bias, unsigned short* __restrict__ Cout,
    int Ncols, int K)
{
  __shared__ alignas(16) unsigned short ldsA[2 * BUFE];
  __shared__ alignas(16) unsigned short ldsB[2 * BUFE];
  floatx4 acc[4][2];
#pragma unroll
  for (int i = 0; i < 4; i++)
#pragma unroll
    for (int j = 0; j < 2; j++)
#pragma unroll
      for (int t = 0; t < 4; t++) acc[i][j][t] = 0.f;

  const int tid  = threadIdx.x;
  const int lane = tid & 63;
  const int wid  = tid >> 6;
  const int wm   = wid & 1;
  const int wn   = wid >> 1;
  const int fr   = lane & 15;
  const int fk   = (lane >> 4) << 3;
  const int lr   = lane >> 2;
  const int lc   = (lane & 3) << 3;
  const int r0   = wid << 4;

  const float* ap = A + ((size_t)blockIdx.x * 128 + r0 + lr) * K + lc;
  const unsigned short* gB = Bw + ((size_t)blockIdx.y * 128 + r0 + lr) * K + lc;
  unsigned short* lB = ldsB + r0 * BKt;
  unsigned short* sa = ldsA + (r0 + lr) * BKt + lc;
  const unsigned short* fa = ldsA + (wm * 64 + fr) * BKt + fk;
  const unsigned short* fb = ldsB + (wn * 32 + fr) * BKt + fk;

  // prologue: stage K-step 0 into buffer 0
  {
    float4 f0 = *(const float4*)(ap);
    float4 f1 = *(const float4*)(ap + 4);
    ap += BKt;
    uint4 pa;
    pa.x = f2bf(f0.x) | ((unsigned)f2bf(f0.y) << 16);
    pa.y = f2bf(f0.z) | ((unsigned)f2bf(f0.w) << 16);
    pa.z = f2bf(f1.x) | ((unsigned)f2bf(f1.y) << 16);
    pa.w = f2bf(f1.z) | ((unsigned)f2bf(f1.w) << 16);
    gload16(gB, lB); gB += BKt;
    *(uint4*)sa = pa;
  }
  __syncthreads();

  int cur = 0;
  for (int k0 = 0; k0 < K; k0 += BKt) {
    const int nxt = cur ^ 1;
    const bool more = (k0 + BKt < K);
    float4 n0, n1;
    if (more) {                        // issue next-tile loads (async-ish)
      n0 = *(const float4*)(ap);
      n1 = *(const float4*)(ap + 4);
      ap += BKt;
      gload16(gB, lB + nxt * BUFE); gB += BKt;
    }
    const unsigned short* fac = fa + cur * BUFE;
    const unsigned short* fbc = fb + cur * BUFE;
    short8 af[4], bfr[2];
#pragma unroll
    for (int i = 0; i < 4; i++) af[i]  = *(const short8*)(fac + i * 16 * BKt);
#pragma unroll
    for (int j = 0; j < 2; j++) bfr[j] = *(const short8*)(fbc + j * 16 * BKt);
#pragma unroll
    for (int i = 0; i < 4; i++)
#pragma unroll
      for (int j = 0; j < 2; j++)
        acc[i][j] = __builtin_amdgcn_mfma_f32_16x16x32_bf16(af[i], bfr[j], acc[i][j], 0, 0, 0);
    if (more) {                        // pack + write-late (before barrier)
      uint4 pa;
      pa.x = f2bf(n0.x) | ((unsigned)f2bf(n0.y) << 16);
      pa.y = f2bf(n0.z) | ((unsigned)f2bf(n0.w) << 16);
      pa.z = f2bf(n1.x) | ((unsigned)f2bf(n1.y) << 16);
      pa.w = f2bf(n1.z) | ((unsigned)f2bf(n1.w) << 16);
      *(uint4*)(sa + nxt * BUFE) = pa;
    }
    __syncthreads();
    cur = nxt;
  }

  const int r4 = (lane >> 4) * 4;
  const int cn = lane & 15;
#pragma unroll
  for (int i = 0; i < 4; i++) {
#pragma unroll
    for (int j = 0; j < 2; j++) {
      int gc = blockIdx.y * 128 + wn * 32 + j * 16 + cn;
      float bv = bias[gc];
#pragma unroll
      for (int r = 0; r < 4; r++) {
        int gr = blockIdx.x * 128 + wm * 64 + i * 16 + r4 + r;
        Cout[(size_t)gr * Ncols + gc] = f2bf(acc[i][j][r] + bv);
      }
    }
  }
}

// ---------------------------------------------------------------------------
// MLP GEMM (bf16 A), 8-wave dbuf. MODE 1: silu -> bf16. MODE 2: store fp32.
// ---------------------------------------------------------------------------
template<int MODE>
__global__ __launch_bounds__(512, 4) void k_gemm_bias(
    const unsigned short* __restrict__ A, const unsigned short* __restrict__ Bw,
    const float* __restrict__ bias, void* __restrict__ Cout, int Ncols, int K)
{
  __shared__ alignas(16) unsigned short ldsA[2 * BUFE];
  __shared__ alignas(16) unsigned short ldsB[2 * BUFE];
  floatx4 acc[4][2];
#pragma unroll
  for (int i = 0; i < 4; i++)
#pragma unroll
    for (int j = 0; j < 2; j++)
#pragma unroll
      for (int t = 0; t < 4; t++) acc[i][j][t] = 0.f;

  const unsigned short* Ab = A + (size_t)blockIdx.x * 128 * K;
  const unsigned short* Bb = Bw + (size_t)blockIdx.y * 128 * K;
  gemm_core8_nt(Ab, K, Bb, K, K, ldsA, ldsB, acc);

  EPILOGUE_VARS
#pragma unroll
  for (int i = 0; i < 4; i++) {
#pragma unroll
    for (int j = 0; j < 2; j++) {
      int gc = blockIdx.y * 128 + wn * 32 + j * 16 + cn;
      float bv = bias[gc];
#pragma unroll
      for (int r = 0; r < 4; r++) {
        int gr = blockIdx.x * 128 + wm * 64 + i * 16 + r4 + r;
        float v = acc[i][j][r] + bv;
        if constexpr (MODE == 1) v = v / (1.f + __expf(-v));
        if constexpr (MODE == 2)
          ((float*)Cout)[(size_t)gr * Ncols + gc] = v;
        else
          ((unsigned short*)Cout)[(size_t)gr * Ncols + gc] = f2bf(v);
      }
    }
  }
}

// ---------------------------------------------------------------------------
// k_sd: FUSED struct+elec GEMMs, one interleaved 8-wave core. Per K-step:
// stage 4 slices (As,Ae,Bs,Be) + 16 MFMA. Writes packed uint32
// (bf16 s/16 | bf16 d), accumulates dsum[b]. Chunk = 4 batches (z=0..3).
// ---------------------------------------------------------------------------
__global__ __launch_bounds__(512, 4) void k_sd(
    const unsigned short* __restrict__ Xq, const unsigned short* __restrict__ Xk,
    const float* __restrict__ q2, const float* __restrict__ k2,
    int b0, float* __restrict__ dsum, unsigned* __restrict__ sd)
{
  __shared__ alignas(16) unsigned short ldsAs[2 * BUFE];
  __shared__ alignas(16) unsigned short ldsAe[2 * BUFE];
  __shared__ alignas(16) unsigned short ldsBs[2 * BUFE];
  __shared__ alignas(16) unsigned short ldsBe[2 * BUFE];
  floatx4 accS[4][2], accE[4][2];
#pragma unroll
  for (int i = 0; i < 4; i++)
#pragma unroll
    for (int j = 0; j < 2; j++)
#pragma unroll
      for (int t = 0; t < 4; t++) { accS[i][j][t] = 0.f; accE[i][j][t] = 0.f; }

  const int z = blockIdx.z;           // chunk-local batch 0..3
  const int b = b0 + z;

  const int tid  = threadIdx.x;
  const int lane = tid & 63;
  const int wid  = tid >> 6;
  const int wm   = wid & 1;
  const int wn   = wid >> 1;
  const int fr   = lane & 15;
  const int fk   = (lane >> 4) << 3;
  const int lr   = lane >> 2;
  const int lc   = (lane & 3) << 3;
  const int r0   = wid << 4;

  const unsigned short* gAs = Xq + ((size_t)(b * Nq) + blockIdx.x * 128 + r0 + lr) * 512 + lc;
  const unsigned short* gAe = gAs + 256;
  const unsigned short* gBs = Xk + ((size_t)(b * Mk) + blockIdx.y * 128 + r0 + lr) * 1024 + lc;
  const unsigned short* gBe = gBs + 512;
  unsigned short* lAs = ldsAs + r0 * BKt;
  unsigned short* lAe = ldsAe + r0 * BKt;
  unsigned short* lBs = ldsBs + r0 * BKt;
  unsigned short* lBe = ldsBe + r0 * BKt;
  const unsigned short* fas = ldsAs + (wm * 64 + fr) * BKt + fk;
  const unsigned short* fae = ldsAe + (wm * 64 + fr) * BKt + fk;
  const unsigned short* fbs = ldsBs + (wn * 32 + fr) * BKt + fk;
  const unsigned short* fbe = ldsBe + (wn * 32 + fr) * BKt + fk;

  // prologue: stage K-step 0 into buffer 0
  gload16(gAs, lAs); gAs += BKt;
  gload16(gAe, lAe); gAe += BKt;
  gload16(gBs, lBs); gBs += BKt;
  gload16(gBe, lBe); gBe += BKt;
  __syncthreads();

  int cur = 0;
  for (int k0 = 0; k0 < 256; k0 += BKt) {
    const int nxt = cur ^ 1;
    if (k0 + BKt < 256) {
      gload16(gAs, lAs + nxt * BUFE); gAs += BKt;
      gload16(gAe, lAe + nxt * BUFE); gAe += BKt;
      gload16(gBs, lBs + nxt * BUFE); gBs += BKt;
      gload16(gBe, lBe + nxt * BUFE); gBe += BKt;
    }
    {   // struct 8 MFMA
      short8 af[4], bfr[2];
      const unsigned short* fac = fas + cur * BUFE;
      const unsigned short* fbc = fbs + cur * BUFE;
#pragma unroll
      for (int i = 0; i < 4; i++) af[i]  = *(const short8*)(fac + i * 16 * BKt);
#pragma unroll
      for (int j = 0; j < 2; j++) bfr[j] = *(const short8*)(fbc + j * 16 * BKt);
#pragma unroll
      for (int i = 0; i < 4; i++)
#pragma unroll
        for (int j = 0; j < 2; j++)
          accS[i][j] = __builtin_amdgcn_mfma_f32_16x16x32_bf16(af[i], bfr[j], accS[i][j], 0, 0, 0);
    }
    {   // elec 8 MFMA
      short8 af[4], bfr[2];
      const unsigned short* fac = fae + cur * BUFE;
      const unsigned short* fbc = fbe + cur * BUFE;
#pragma unroll
      for (int i = 0; i < 4; i++) af[i]  = *(const short8*)(fac + i * 16 * BKt);
#pragma unroll
      for (int j = 0; j < 2; j++) bfr[j] = *(const short8*)(fbc + j * 16 * BKt);
#pragma unroll
      for (int i = 0; i < 4; i++)
#pragma unroll
        for (int j = 0; j < 2; j++)
          accE[i][j] = __builtin_amdgcn_mfma_f32_16x16x32_bf16(af[i], bfr[j], accE[i][j], 0, 0, 0);
    }
    __syncthreads();
    cur = nxt;
  }

  const int r4 = (lane >> 4) * 4;
  const int cn = lane & 15;
  const int colT = blockIdx.y * 128 + wn * 32;
  const float kk0 = k2[b * Mk + colT + cn];
  const float kk1 = k2[b * Mk + colT + 16 + cn];

  float lsum = 0.f;
#pragma unroll
  for (int i = 0; i < 4; i++) {
#pragma unroll
    for (int r = 0; r < 4; r++) {
      const int n = blockIdx.x * 128 + wm * 64 + i * 16 + r4 + r;
      const float qq = q2[b * Nq + n];
      unsigned* srow = sd + (size_t)(z * Nq + n) * Mk;
#pragma unroll
      for (int j = 0; j < 2; j++) {
        const int m = colT + j * 16 + cn;
        float d = sqrtf(fmaxf(qq + (j ? kk1 : kk0) - 2.f * accE[i][j][r], 1e-12f));
        lsum += d;
        srow[m] = (unsigned)f2bf(accS[i][j][r] * 0.0625f)
                | ((unsigned)f2bf(d) << 16);
      }
    }
  }
#pragma unroll
  for (int o = 32; o; o >>= 1) lsum += __shfl_down(lsum, o);
  __syncthreads();                    // LDS frag reads done before reuse
  float* red = (float*)ldsAs;
  if (lane == 0) red[wid] = lsum;
  __syncthreads();
  if (threadIdx.x == 0) {
    float s = 0.f;
#pragma unroll
    for (int t = 0; t < 8; t++) s += red[t];
    atomicAdd(dsum + b, s);
  }
}

// ---------------------------------------------------------------------------
// k_pvf: fused softmax + PV + feature-concat (flash-style, no attn buffer).
// Block = 32 q-rows x all 512 V-cols, one batch; grid 256 (64 stripes x 4
// chunk-batches, z=bid&3 for XCD-batch affinity). Per 64-m tile: stream
// sd+pi -> e in regs -> swizzled dbuf LDS e-tile (A operand) -> 16 MFMA/wave
// vs VT frags read directly from global (L2-resident). Rowsum block-local.
// Epilogue: fused[row] = [cs|ce|cs-ce|cs*ce] / rs.
// Waves 2x4: wm row-group (16 rows), wn col-group: frags j=0..3 struct cols
// wn*64+j*16, j=4..7 elec cols 256+wn*64+(j-4)*16.
// ---------------------------------------------------------------------------
__global__ __launch_bounds__(512, 2) void k_pvf(
    const unsigned* __restrict__ sd, const float* __restrict__ pi,
    const unsigned short* __restrict__ VT,
    const float* __restrict__ dsum, const float* __restrict__ gamma_p,
    const float* __restrict__ ew_p, int b0,
    unsigned short* __restrict__ fused)
{
  __shared__ alignas(16) unsigned short eld[2][32 * 64];  // swizzled e-tiles
  __shared__ float rsum[32];

  const int bid    = blockIdx.x;
  const int z      = bid & 3;          // chunk-local batch (XCD-affine)
  const int stripe = bid >> 2;         // 0..63
  const int b      = b0 + z;
  const int n0     = stripe * 32;

  const int tid  = threadIdx.x;
  const int lane = tid & 63;
  const int wid  = tid >> 6;
  const int wm   = wid & 1;
  const int wn   = wid >> 1;
  const int fr   = lane & 15;
  const int fk8  = (lane >> 4) << 3;   // lane's m-slice within a k-step

  const float scale = fmaxf(dsum[b] * (1.f / (2048.f * 2048.f)), 1e-4f);
  const float einv  = ew_p[0] / scale;
  const float gv    = gamma_p[0];
  const bool  g1    = (gv == 1.0f);

  floatx4 acc[8];
#pragma unroll
  for (int j = 0; j < 8; ++j)
#pragma unroll
    for (int t = 0; t < 4; ++t) acc[j][t] = 0.f;

  // ---- staging mapping: thread -> (row = tid>>4, 4 m-values at (tid&15)*4)
  const int srow = tid >> 4;           // 0..31 (fixed across iterations)
  const int sm   = (tid & 15) << 2;
  const unsigned* sp = sd + ((size_t)(z * Nq) + n0 + srow) * (size_t)Mk + sm;
  const float*    pp = pi + ((size_t)(b * Nq) + n0 + srow) * (size_t)Mk + sm;
  // swizzled LDS write index (ushorts): byte = srow*128 + (sm*2 ^ ((srow&7)<<4))
  const int wIdx = (srow * 128 + ((sm * 2) ^ ((srow & 7) << 4))) >> 1;

  // ---- A-frag read indices (ushorts), swizzle-matched, per k-step
  const int arow  = wm * 16 + fr;
  const int aIdx0 = (arow * 128 + ((((lane >> 4) << 4) + 0 ) ^ ((arow & 7) << 4))) >> 1;
  const int aIdx1 = (arow * 128 + ((((lane >> 4) << 4) + 64) ^ ((arow & 7) << 4))) >> 1;

  // ---- B pointers: VT[b*512 + vrow][m], advance 64/iter
  const unsigned short* bp[8];
#pragma unroll
  for (int j = 0; j < 8; ++j) {
    const int vrow = (j < 4) ? (wn * 64 + j * 16 + fr)
                             : (256 + wn * 64 + (j - 4) * 16 + fr);
    bp[j] = VT + ((size_t)b * 512 + vrow) * (size_t)Mk + fk8;
  }

  float rs = 0.f;

#define E_COMPUTE_STORE(SV, PV, BUF) do {                                    \
    const unsigned uu_[4] = {(SV).x, (SV).y, (SV).z, (SV).w};                \
    const float    pf_[4] = {(PV).x, (PV).y, (PV).z, (PV).w};                \
    float e_[4];                                                             \
    _Pragma("unroll")                                                        \
    for (int t_ = 0; t_ < 4; ++t_) {                                         \
      union { unsigned u; float f; } cs_, cd_;                               \
      cs_.u = uu_[t_] << 16;                                                 \
      cd_.u = uu_[t_] & 0xffff0000u;                                         \
      float p_  = fmaxf(pf_[t_], 1e-9f);                                     \
      float pw_ = g1 ? p_ : __expf(gv * __logf(p_));                         \
      e_[t_] = __expf(cs_.f - einv * cd_.f) * pw_;                           \
      rs += e_[t_];                                                          \
    }                                                                        \
    uint2 st_;                                                               \
    st_.x = (unsigned)f2bf(e_[0]) | ((unsigned)f2bf(e_[1]) << 16);           \
    st_.y = (unsigned)f2bf(e_[2]) | ((unsigned)f2bf(e_[3]) << 16);           \
    *(uint2*)(&eld[BUF][wIdx]) = st_;                                        \
  } while (0)

  // prologue: tile 0 -> LDS[0]; preload tile 1 regs
  uint4  sv = *(const uint4*)sp;  sp += 64;
  float4 pv = *(const float4*)pp; pp += 64;
  E_COMPUTE_STORE(sv, pv, 0);
  uint4  svn = *(const uint4*)sp;  sp += 64;
  float4 pvn = *(const float4*)pp; pp += 64;
  __syncthreads();

  int cur = 0;
  for (int t = 0; t < 32; ++t) {
    // MFMA phase on eld[cur] (2 k-steps x 8 MFMA, af shared per k-step)
    short8 af0 = *(const short8*)(&eld[cur][aIdx0]);
    short8 af1 = *(const short8*)(&eld[cur][aIdx1]);
#pragma unroll
    for (int j = 0; j < 8; ++j) {
      short8 bf0 = *(const short8*)(bp[j]);
      acc[j] = __builtin_amdgcn_mfma_f32_16x16x32_bf16(af0, bf0, acc[j], 0, 0, 0);
    }
#pragma unroll
    for (int j = 0; j < 8; ++j) {
      short8 bf1 = *(const short8*)(bp[j] + 32);
      acc[j] = __builtin_amdgcn_mfma_f32_16x16x32_bf16(af1, bf1, acc[j], 0, 0, 0);
      bp[j] += 64;
    }
    // overlap: build tile t+1 in the other buffer; prefetch tile t+2 regs
    if (t < 31) {
      E_COMPUTE_STORE(svn, pvn, cur ^ 1);
      if (t < 30) {
        svn = *(const uint4*)sp;  sp += 64;
        pvn = *(const float4*)pp; pp += 64;
      }
    }
    __syncthreads();
    cur ^= 1;
  }
#undef E_COMPUTE_STORE

  // ---- full rowsums (block spans all m): reduce 16 staging lanes per row
  rs += __shfl_xor(rs, 1);
  rs += __shfl_xor(rs, 2);
  rs += __shfl_xor(rs, 4);
  rs += __shfl_xor(rs, 8);
  if ((tid & 15) == 0) rsum[srow] = rs;
  __syncthreads();

  // ---- epilogue: normalize + concat features
  const int r4 = (lane >> 4) * 4;
  const int cn = lane & 15;
#pragma unroll
  for (int rr = 0; rr < 4; ++rr) {
    const int row = wm * 16 + r4 + rr;
    const float rinv = 1.f / rsum[row];
    unsigned short* out = fused + ((size_t)(b * Nq) + n0 + row) * 1024;
#pragma unroll
    for (int j = 0; j < 4; ++j) {
      const int col = wn * 64 + j * 16 + cn;
      const float cs = acc[j][rr] * rinv;
      const float ce = acc[j + 4][rr] * rinv;
      out[col]       = f2bf(cs);
      out[col + 256] = f2bf(ce);
      out[col + 512] = f2bf(cs - ce);
      out[col + 768] = f2bf(cs * ce);
    }
  }
}

// ---------------------------------------------------------------------------
// Small utility kernels
// ---------------------------------------------------------------------------
// transpose + concat weights -> bf16; concat biases; zero dsum
__global__ void k_prep_w(
    const float* __restrict__ Wqs, const float* __restrict__ Wqe,
    const float* __restrict__ Wks, const float* __restrict__ Wvs,
    const float* __restrict__ Wke, const float* __restrict__ Wve,
    const float* __restrict__ W1,  const float* __restrict__ W2,
    const float* __restrict__ bqs, const float* __restrict__ bqe,
    const float* __restrict__ bks, const float* __restrict__ bvs,
    const float* __restrict__ bke, const float* __restrict__ bve,
    unsigned short* __restrict__ WqT, unsigned short* __restrict__ WkT,
    unsigned short* __restrict__ W1T, unsigned short* __restrict__ W2T,
    float* __restrict__ bq, float* __restrict__ bk, float* __restrict__ dsum)
{
  int gid = blockIdx.x * 256 + threadIdx.x;
  int idx = gid;
  if (idx < 512 * 512) {                       // WqT[j,k], j: qs|qe
    int j = idx >> 9, k = idx & 511;
    float v = (j < 256) ? Wqs[k * 256 + j] : Wqe[k * 256 + (j - 256)];
    WqT[idx] = f2bf(v);
  } else if ((idx -= 512 * 512) < 1024 * 512) { // WkT[j,k], j: ks|vs|ke|ve
    int j = idx >> 9, k = idx & 511;
    int s = j >> 8, jj = j & 255;
    const float* Wp = (s == 0) ? Wks : (s == 1) ? Wvs : (s == 2) ? Wke : Wve;
    WkT[idx] = f2bf(Wp[k * 256 + jj]);
  } else if ((idx -= 1024 * 512) < 256 * 1024) { // W1T[j,k]
    int j = idx >> 10, k = idx & 1023;
    W1T[idx] = f2bf(W1[k * 256 + j]);
  } else if ((idx -= 256 * 1024) < 256 * 256) {  // W2T[j,k]
    int j = idx >> 8, k = idx & 255;
    W2T[idx] = f2bf(W2[k * 256 + j]);
  }
  if (gid < 512)  bq[gid] = (gid < 256) ? bqs[gid] : bqe[gid - 256];
  if (gid < 1024) bk[gid] = (gid < 256) ? bks[gid]
                    : (gid < 512) ? bvs[gid - 256]
                    : (gid < 768) ? bke[gid - 512] : bve[gid - 768];
  if (gid < 8) dsum[gid] = 0.f;
}

// row sum-of-squares over 256 bf16 columns (one wave per row)
__global__ __launch_bounds__(256) void k_rowsq(
    const unsigned short* __restrict__ X, int stride, int colOff, float* __restrict__ out)
{
  int row = blockIdx.x * 4 + (threadIdx.x >> 6);
  int lane = threadIdx.x & 63;
  const unsigned short* p = X + (size_t)row * stride + colOff + lane * 4;
  uint2 u = *(const uint2*)p;
  float a0 = bf2f((unsigned short)(u.x & 0xffff));
  float a1 = bf2f((unsigned short)(u.x >> 16));
  float a2 = bf2f((unsigned short)(u.y & 0xffff));
  float a3 = bf2f((unsigned short)(u.y >> 16));
  float s = a0 * a0 + a1 * a1 + a2 * a2 + a3 * a3;
#pragma unroll
  for (int o = 32; o; o >>= 1) s += __shfl_down(s, o);
  if (lane == 0) out[row] = s;
}

// VT[b, j, m] = Xk[b*M+m, (j<256)?256+j:512+j]  (v_struct | v_elec transposed)
__global__ void k_trans_vt(const unsigned short* __restrict__ Xk, unsigned short* __restrict__ VT) {
  __shared__ unsigned short t[32][33];
  const int b = blockIdx.z;
  const int m0 = blockIdx.x * 32, j0 = blockIdx.y * 32;
  const int tx = threadIdx.x, ty = threadIdx.y;
#pragma unroll
  for (int i = 0; i < 4; i++) {
    int m = m0 + ty + i * 8;
    int j = j0 + tx;
    int c = (j < 256) ? (256 + j) : (512 + j);
    t[ty + i * 8][tx] = Xk[((size_t)b * Mk + m) * 1024 + c];
  }
  __syncthreads();
#pragma unroll
  for (int i = 0; i < 4; i++) {
    int j = j0 + ty + i * 8;
    int m = m0 + tx;
    VT[((size_t)b * 512 + j) * Mk + m] = t[tx][ty + i * 8];
  }
}

// ---------------------------------------------------------------------------
extern "C" void kernel_launch(void* const* d_in, const int* in_sizes, int n_in,
                              void* d_out, int out_size, void* d_ws, size_t ws_size,
                              hipStream_t stream) {
  (void)in_sizes; (void)n_in; (void)out_size; (void)ws_size;
  const float* q_fp  = (const float*)d_in[0];
  const float* v_ret = (const float*)d_in[1];
  const float* pi    = (const float*)d_in[2];
  const float* Wqs = (const float*)d_in[3];  const float* bqs = (const float*)d_in[4];
  const float* Wks = (const float*)d_in[5];  const float* bks = (const float*)d_in[6];
  const float* Wvs = (const float*)d_in[7];  const float* bvs = (const float*)d_in[8];
  const float* Wqe = (const float*)d_in[9];  const float* bqe = (const float*)d_in[10];
  const float* Wke = (const float*)d_in[11]; const float* bke = (const float*)d_in[12];
  const float* Wve = (const float*)d_in[13]; const float* bve = (const float*)d_in[14];
  const float* W1  = (const float*)d_in[15]; const float* b1  = (const float*)d_in[16];
  const float* W2  = (const float*)d_in[17]; const float* b2  = (const float*)d_in[18];
  const float* gamma = (const float*)d_in[19];
  const float* ew    = (const float*)d_in[20];

  char* w = (char*)d_ws;
  unsigned short* WqT = (unsigned short*)(w + 0);          // 512x512 bf16
  unsigned short* WkT = (unsigned short*)(w + 524288);     // 1024x512
  unsigned short* W1T = (unsigned short*)(w + 1572864);    // 256x1024
  unsigned short* W2T = (unsigned short*)(w + 2097152);    // 256x256
  float* bq   = (float*)(w + 2228224);                     // 512
  float* bk   = (float*)(w + 2230272);                     // 1024
  float* q2   = (float*)(w + 2234368);                     // 16384
  float* k2   = (float*)(w + 2299904);                     // 16384
  float* dsum = (float*)(w + 2365440);                     // 8
  unsigned short* fused = (unsigned short*)(w + 2365696);  // 16384x1024 bf16 (33.6MB) -> ends 35920128
  unsigned short* Xq = (unsigned short*)(w + 35920128);    // 16384x512 (qs|qe)
  unsigned short* Xk = (unsigned short*)(w + 52697344);    // 16384x1024 (ks|vs|ke|ve)
  unsigned short* VT = (unsigned short*)(w + 86251776);    // 8x512x2048 (16.8MB) -> ends 103028992
  unsigned* sdbuf = (unsigned*)(w + 103028992);            // 4 batches x 2048x2048 u32 = 67.1MB (old attn slot)
  unsigned short* hbuf = (unsigned short*)(w + 103028992); // 16384x256 bf16 (8.4MB), reuses sdbuf after chunks

  k_prep_w<<<4352, 256, 0, stream>>>(Wqs, Wqe, Wks, Wvs, Wke, Wve, W1, W2,
                                     bqs, bqe, bks, bvs, bke, bve,
                                     WqT, WkT, W1T, W2T, bq, bk, dsum);
  // projections straight from fp32 inputs: Xq=[q_struct|q_elec], Xk=[ks|vs|ke|ve]
  k_proj<<<dim3(128, 4), 512, 0, stream>>>(q_fp,  WqT, bq, Xq, 512, 512);
  k_proj<<<dim3(128, 8), 512, 0, stream>>>(v_ret, WkT, bk, Xk, 1024, 512);
  k_rowsq<<<4096, 256, 0, stream>>>(Xq, 512, 256, q2);
  k_rowsq<<<4096, 256, 0, stream>>>(Xk, 1024, 512, k2);
  // transpose v_struct/v_elec -> VT (needed inside chunk loop)
  k_trans_vt<<<dim3(64, 16, 8), dim3(32, 8), 0, stream>>>(Xk, VT);
  // chunked (4 batches each): fused GEMMs -> packed (s,d); then flash PV
  for (int c = 0; c < 2; ++c) {
    k_sd<<<dim3(16, 16, 4), 512, 0, stream>>>(Xq, Xk, q2, k2, 4 * c, dsum, sdbuf);
    k_pvf<<<256, 512, 0, stream>>>(sdbuf, pi, VT, dsum, gamma, ew, 4 * c, fused);
  }
  // MLP: h = silu(fused @ W1 + b1); out = h @ W2 + b2 (fp32)
  k_gemm_bias<1><<<dim3(128, 2), 512, 0, stream>>>(fused, W1T, b1, hbuf, 256, 1024);
  k_gemm_bias<2><<<dim3(128, 2), 512, 0, stream>>>(hbuf, W2T, b2, d_out, 256, 256);
}

// Round 8
// 559.389 us; speedup vs baseline: 1.4058x; 1.4058x over previous
//
#include <hip/hip_runtime.h>

// PGWCrossAttention on MI355X (gfx950), bf16 MFMA pipeline.
// R12: REVERT R11's k_pvf (209us/dispatch: 1 block/CU + per-MFMA global B
// loads = serial latency chain; MfmaUtil 3.2%). Back to proven R10b pipeline
// (571.7us) + one mechanistic win: k_proj's in-loop fp32->bf16 packing
// (~20 VALU ops/thread/K-step, serial with MFMA) replaced by a 16us streaming
// cast pass; both projections now run the proven pure-bf16 k_gemm_bias<0>
// core (gload16 both operands, dbuf). Cast buffers live in the attn slot
// (dead until k_softmax).
#define Bsz 8
#define Nq  2048
#define Mk  2048
#define BKt 32          // K-tile per MFMA step
#define BUFE (128 * BKt) // elements per LDS buffer

typedef __attribute__((ext_vector_type(8))) short   short8;   // 8 bf16 (4 VGPRs)
typedef __attribute__((ext_vector_type(4))) float   floatx4;  // MFMA acc

__device__ __forceinline__ unsigned short f2bf(float f) {
  union { float f; unsigned u; } x; x.f = f;
  unsigned r = x.u + 0x7fffu + ((x.u >> 16) & 1u);   // RNE
  return (unsigned short)(r >> 16);
}
__device__ __forceinline__ float bf2f(unsigned short s) {
  union { unsigned u; float f; } x; x.u = ((unsigned)s) << 16;
  return x.f;
}

// async global->LDS, 16B per lane. LDS dest is wave-uniform base + lane*16.
__device__ __forceinline__ void gload16(const unsigned short* g, unsigned short* l) {
  __builtin_amdgcn_global_load_lds(
      (const __attribute__((address_space(1))) void*)g,
      (__attribute__((address_space(3))) void*)l, 16, 0, 0);
}

// ---------------------------------------------------------------------------
// 8-wave NT GEMM core 128x128, double-buffered: C += A[128,K] . B[128,K]^T.
// 512 threads, waves 2x4, wave tile 64x32, acc[4][2].
// ---------------------------------------------------------------------------
__device__ __forceinline__ void gemm_core8_nt(
    const unsigned short* __restrict__ A, int lda,
    const unsigned short* __restrict__ B, int ldb,
    int K, unsigned short* ldsA, unsigned short* ldsB,
    floatx4 (&acc)[4][2])
{
  const int tid  = threadIdx.x;
  const int lane = tid & 63;
  const int wid  = tid >> 6;          // 0..7
  const int wm   = wid & 1;
  const int wn   = wid >> 1;          // 0..3
  const int fr   = lane & 15;
  const int fk   = (lane >> 4) << 3;
  const int lr   = lane >> 2;         // 0..15
  const int lc   = (lane & 3) << 3;   // 0/8/16/24
  const int r0   = wid << 4;          // 16 rows per wave

  const unsigned short* gA = A + (size_t)(r0 + lr) * lda + lc;
  const unsigned short* gB = B + (size_t)(r0 + lr) * ldb + lc;
  unsigned short* lA = ldsA + r0 * BKt;
  unsigned short* lB = ldsB + r0 * BKt;
  const unsigned short* fa = ldsA + (wm * 64 + fr) * BKt + fk;
  const unsigned short* fb = ldsB + (wn * 32 + fr) * BKt + fk;

  // prologue: stage K-step 0 into buffer 0
  gload16(gA, lA); gA += BKt;
  gload16(gB, lB); gB += BKt;
  __syncthreads();

  int cur = 0;
  for (int k0 = 0; k0 < K; k0 += BKt) {
    const int nxt = cur ^ 1;
    if (k0 + BKt < K) {               // issue next-tile prefetch (async)
      gload16(gA, lA + nxt * BUFE); gA += BKt;
      gload16(gB, lB + nxt * BUFE); gB += BKt;
    }
    const unsigned short* fac = fa + cur * BUFE;
    const unsigned short* fbc = fb + cur * BUFE;
    short8 af[4], bfr[2];
#pragma unroll
    for (int i = 0; i < 4; i++) af[i]  = *(const short8*)(fac + i * 16 * BKt);
#pragma unroll
    for (int j = 0; j < 2; j++) bfr[j] = *(const short8*)(fbc + j * 16 * BKt);
#pragma unroll
    for (int i = 0; i < 4; i++)
#pragma unroll
      for (int j = 0; j < 2; j++)
        acc[i][j] = __builtin_amdgcn_mfma_f32_16x16x32_bf16(af[i], bfr[j], acc[i][j], 0, 0, 0);
    __syncthreads();                  // drains prefetch; buf safe to overwrite
    cur = nxt;
  }
}

#define EPILOGUE_VARS \
  const int lane = threadIdx.x & 63; \
  const int wid  = threadIdx.x >> 6; \
  const int wm   = wid & 1; \
  const int wn   = wid >> 1; \
  const int r4   = (lane >> 4) * 4;  \
  const int cn   = lane & 15; \
  (void)wid;

// ---------------------------------------------------------------------------
// GEMM + bias (bf16 A), 8-wave dbuf. MODE 0: bf16 store (projections).
// MODE 1: silu -> bf16. MODE 2: store fp32.
// ---------------------------------------------------------------------------
template<int MODE>
__global__ __launch_bounds__(512, 4) void k_gemm_bias(
    const unsigned short* __restrict__ A, const unsigned short* __restrict__ Bw,
    const float* __restrict__ bias, void* __restrict__ Cout, int Ncols, int K)
{
  __shared__ alignas(16) unsigned short ldsA[2 * BUFE];
  __shared__ alignas(16) unsigned short ldsB[2 * BUFE];
  floatx4 acc[4][2];
#pragma unroll
  for (int i = 0; i < 4; i++)
#pragma unroll
    for (int j = 0; j < 2; j++)
#pragma unroll
      for (int t = 0; t < 4; t++) acc[i][j][t] = 0.f;

  const unsigned short* Ab = A + (size_t)blockIdx.x * 128 * K;
  const unsigned short* Bb = Bw + (size_t)blockIdx.y * 128 * K;
  gemm_core8_nt(Ab, K, Bb, K, K, ldsA, ldsB, acc);

  EPILOGUE_VARS
#pragma unroll
  for (int i = 0; i < 4; i++) {
#pragma unroll
    for (int j = 0; j < 2; j++) {
      int gc = blockIdx.y * 128 + wn * 32 + j * 16 + cn;
      float bv = bias[gc];
#pragma unroll
      for (int r = 0; r < 4; r++) {
        int gr = blockIdx.x * 128 + wm * 64 + i * 16 + r4 + r;
        float v = acc[i][j][r] + bv;
        if constexpr (MODE == 1) v = v / (1.f + __expf(-v));
        if constexpr (MODE == 2)
          ((float*)Cout)[(size_t)gr * Ncols + gc] = v;
        else
          ((unsigned short*)Cout)[(size_t)gr * Ncols + gc] = f2bf(v);
      }
    }
  }
}

// ---------------------------------------------------------------------------
// k_cast: fp32 -> bf16 streaming (8 elems/thread, grid-stride).
// ---------------------------------------------------------------------------
__global__ __launch_bounds__(512) void k_cast(
    const float* __restrict__ src, unsigned short* __restrict__ dst, int n8)
{
  for (int i = blockIdx.x * 512 + threadIdx.x; i < n8; i += gridDim.x * 512) {
    const float4 f0 = *(const float4*)(src + (size_t)i * 8);
    const float4 f1 = *(const float4*)(src + (size_t)i * 8 + 4);
    uint4 p;
    p.x = f2bf(f0.x) | ((unsigned)f2bf(f0.y) << 16);
    p.y = f2bf(f0.z) | ((unsigned)f2bf(f0.w) << 16);
    p.z = f2bf(f1.x) | ((unsigned)f2bf(f1.y) << 16);
    p.w = f2bf(f1.z) | ((unsigned)f2bf(f1.w) << 16);
    *(uint4*)(dst + (size_t)i * 8) = p;
  }
}

// ---------------------------------------------------------------------------
// k_sd: FUSED struct+elec GEMMs, one interleaved 8-wave core. Per K-step:
// stage 4 slices (As,Ae,Bs,Be) + 16 MFMA. Writes packed uint32
// (bf16 s/16 | bf16 d), accumulates dsum[b]. Chunk = 2 batches (z=0/1).
// ---------------------------------------------------------------------------
__global__ __launch_bounds__(512, 4) void k_sd(
    const unsigned short* __restrict__ Xq, const unsigned short* __restrict__ Xk,
    const float* __restrict__ q2, const float* __restrict__ k2,
    int b0, float* __restrict__ dsum, unsigned* __restrict__ sd)
{
  __shared__ alignas(16) unsigned short ldsAs[2 * BUFE];
  __shared__ alignas(16) unsigned short ldsAe[2 * BUFE];
  __shared__ alignas(16) unsigned short ldsBs[2 * BUFE];
  __shared__ alignas(16) unsigned short ldsBe[2 * BUFE];
  floatx4 accS[4][2], accE[4][2];
#pragma unroll
  for (int i = 0; i < 4; i++)
#pragma unroll
    for (int j = 0; j < 2; j++)
#pragma unroll
      for (int t = 0; t < 4; t++) { accS[i][j][t] = 0.f; accE[i][j][t] = 0.f; }

  const int z = blockIdx.z;           // chunk-local batch 0/1
  const int b = b0 + z;

  const int tid  = threadIdx.x;
  const int lane = tid & 63;
  const int wid  = tid >> 6;
  const int wm   = wid & 1;
  const int wn   = wid >> 1;
  const int fr   = lane & 15;
  const int fk   = (lane >> 4) << 3;
  const int lr   = lane >> 2;
  const int lc   = (lane & 3) << 3;
  const int r0   = wid << 4;

  const unsigned short* gAs = Xq + ((size_t)(b * Nq) + blockIdx.x * 128 + r0 + lr) * 512 + lc;
  const unsigned short* gAe = gAs + 256;
  const unsigned short* gBs = Xk + ((size_t)(b * Mk) + blockIdx.y * 128 + r0 + lr) * 1024 + lc;
  const unsigned short* gBe = gBs + 512;
  unsigned short* lAs = ldsAs + r0 * BKt;
  unsigned short* lAe = ldsAe + r0 * BKt;
  unsigned short* lBs = ldsBs + r0 * BKt;
  unsigned short* lBe = ldsBe + r0 * BKt;
  const unsigned short* fas = ldsAs + (wm * 64 + fr) * BKt + fk;
  const unsigned short* fae = ldsAe + (wm * 64 + fr) * BKt + fk;
  const unsigned short* fbs = ldsBs + (wn * 32 + fr) * BKt + fk;
  const unsigned short* fbe = ldsBe + (wn * 32 + fr) * BKt + fk;

  // prologue: stage K-step 0 into buffer 0
  gload16(gAs, lAs); gAs += BKt;
  gload16(gAe, lAe); gAe += BKt;
  gload16(gBs, lBs); gBs += BKt;
  gload16(gBe, lBe); gBe += BKt;
  __syncthreads();

  int cur = 0;
  for (int k0 = 0; k0 < 256; k0 += BKt) {
    const int nxt = cur ^ 1;
    if (k0 + BKt < 256) {
      gload16(gAs, lAs + nxt * BUFE); gAs += BKt;
      gload16(gAe, lAe + nxt * BUFE); gAe += BKt;
      gload16(gBs, lBs + nxt * BUFE); gBs += BKt;
      gload16(gBe, lBe + nxt * BUFE); gBe += BKt;
    }
    {   // struct 8 MFMA
      short8 af[4], bfr[2];
      const unsigned short* fac = fas + cur * BUFE;
      const unsigned short* fbc = fbs + cur * BUFE;
#pragma unroll
      for (int i = 0; i < 4; i++) af[i]  = *(const short8*)(fac + i * 16 * BKt);
#pragma unroll
      for (int j = 0; j < 2; j++) bfr[j] = *(const short8*)(fbc + j * 16 * BKt);
#pragma unroll
      for (int i = 0; i < 4; i++)
#pragma unroll
        for (int j = 0; j < 2; j++)
          accS[i][j] = __builtin_amdgcn_mfma_f32_16x16x32_bf16(af[i], bfr[j], accS[i][j], 0, 0, 0);
    }
    {   // elec 8 MFMA
      short8 af[4], bfr[2];
      const unsigned short* fac = fae + cur * BUFE;
      const unsigned short* fbc = fbe + cur * BUFE;
#pragma unroll
      for (int i = 0; i < 4; i++) af[i]  = *(const short8*)(fac + i * 16 * BKt);
#pragma unroll
      for (int j = 0; j < 2; j++) bfr[j] = *(const short8*)(fbc + j * 16 * BKt);
#pragma unroll
      for (int i = 0; i < 4; i++)
#pragma unroll
        for (int j = 0; j < 2; j++)
          accE[i][j] = __builtin_amdgcn_mfma_f32_16x16x32_bf16(af[i], bfr[j], accE[i][j], 0, 0, 0);
    }
    __syncthreads();
    cur = nxt;
  }

  const int r4 = (lane >> 4) * 4;
  const int cn = lane & 15;
  const int colT = blockIdx.y * 128 + wn * 32;
  const float kk0 = k2[b * Mk + colT + cn];
  const float kk1 = k2[b * Mk + colT + 16 + cn];

  float lsum = 0.f;
#pragma unroll
  for (int i = 0; i < 4; i++) {
#pragma unroll
    for (int r = 0; r < 4; r++) {
      const int n = blockIdx.x * 128 + wm * 64 + i * 16 + r4 + r;
      const float qq = q2[b * Nq + n];
      unsigned* srow = sd + (size_t)(z * Nq + n) * Mk;
#pragma unroll
      for (int j = 0; j < 2; j++) {
        const int m = colT + j * 16 + cn;
        float d = sqrtf(fmaxf(qq + (j ? kk1 : kk0) - 2.f * accE[i][j][r], 1e-12f));
        lsum += d;
        srow[m] = (unsigned)f2bf(accS[i][j][r] * 0.0625f)
                | ((unsigned)f2bf(d) << 16);
      }
    }
  }
#pragma unroll
  for (int o = 32; o; o >>= 1) lsum += __shfl_down(lsum, o);
  __syncthreads();                    // LDS frag reads done before reuse
  float* red = (float*)ldsAs;
  if (lane == 0) red[wid] = lsum;
  __syncthreads();
  if (threadIdx.x == 0) {
    float s = 0.f;
#pragma unroll
    for (int t = 0; t < 8; t++) s += red[t];
    atomicAdd(dsum + b, s);
  }
}

// ---------------------------------------------------------------------------
// k_softmax: streaming. One wave per row: e = exp(s - ew*d/scale) * pi^gamma,
// attn (bf16 unnorm) + rowsum[row] (direct store, no atomics). Fully coalesced.
// ---------------------------------------------------------------------------
__global__ __launch_bounds__(256) void k_softmax(
    const unsigned* __restrict__ sd, const float* __restrict__ pi,
    const float* __restrict__ dsum, const float* __restrict__ gamma_p,
    const float* __restrict__ ew_p, int b0,
    unsigned short* __restrict__ attn, float* __restrict__ rowsum)
{
  const int wid  = threadIdx.x >> 6;
  const int lane = threadIdx.x & 63;
  const int rl   = blockIdx.x * 4 + wid;     // chunk-local row 0..4095
  const int b    = b0 + (rl >> 11);
  const int n    = rl & 2047;

  const float scale = fmaxf(dsum[b] * (1.f / (2048.f * 2048.f)), 1e-4f);
  const float einv  = ew_p[0] / scale;
  const float gv    = gamma_p[0];
  const bool  g1    = (gv == 1.0f);          // wave-uniform fast path

  const unsigned*  sp = sd  + (size_t)rl * Mk;
  const float*     pp = pi  + ((size_t)b * Nq + n) * Mk;
  unsigned short*  ap = attn + ((size_t)b * Nq + n) * Mk;

  float rs = 0.f;
  for (int it = 0; it < 8; ++it) {
    const int c = it * 256 + lane * 4;
    const uint4  sv = *(const uint4*)(sp + c);
    const float4 pv = *(const float4*)(pp + c);
    const unsigned uu[4]  = {sv.x, sv.y, sv.z, sv.w};
    const float    pp4[4] = {pv.x, pv.y, pv.z, pv.w};
    float e[4];
#pragma unroll
    for (int t = 0; t < 4; ++t) {
      union { unsigned u; float f; } cs, cd;
      cs.u = uu[t] << 16;                    // s * 0.0625
      cd.u = uu[t] & 0xffff0000u;            // d
      float p  = fmaxf(pp4[t], 1e-9f);
      float pf = g1 ? p : __expf(gv * __logf(p));
      e[t] = __expf(cs.f - einv * cd.f) * pf;
      rs += e[t];
    }
    uint2 st;
    st.x = (unsigned)f2bf(e[0]) | ((unsigned)f2bf(e[1]) << 16);
    st.y = (unsigned)f2bf(e[2]) | ((unsigned)f2bf(e[3]) << 16);
    *(uint2*)(ap + c) = st;
  }
#pragma unroll
  for (int o = 32; o; o >>= 1) rs += __shfl_down(rs, o);
  if (lane == 0) rowsum[b * Nq + n] = rs;
}

// ---------------------------------------------------------------------------
// PV: ctx[b,n,gc] = (attn_unnorm @ [Vs|Ve]) / rowsum[n]. 128x128 tile, 8 waves.
// XCD swizzle: per-z 64 blocks; lg = (l&7)*8 + l/8 -> XCD c gets row-tiles
// {2c,2c+1} x all 4 col-tiles (attn panels L2-resident).
// ---------------------------------------------------------------------------
__global__ __launch_bounds__(512, 4) void k_pv(
    const unsigned short* __restrict__ At, const unsigned short* __restrict__ VT,
    const float* __restrict__ rowsum, unsigned short* __restrict__ ctx)
{
  __shared__ alignas(16) unsigned short ldsA[2 * BUFE];
  __shared__ alignas(16) unsigned short ldsB[2 * BUFE];
  floatx4 acc[4][2];
#pragma unroll
  for (int i = 0; i < 4; i++)
#pragma unroll
    for (int j = 0; j < 2; j++)
#pragma unroll
      for (int t = 0; t < 4; t++) acc[i][j][t] = 0.f;

  const int l  = blockIdx.x;            // 0..63
  const int lg = ((l & 7) << 3) | (l >> 3);
  const int tx = lg >> 2;               // row tile 0..15
  const int ty = lg & 3;                // col tile 0..3
  const int b  = blockIdx.z;
  const unsigned short* Ab = At + ((size_t)b * Nq + tx * 128) * (size_t)Mk;
  const unsigned short* Bb = VT + ((size_t)b * 512 + ty * 128) * (size_t)Mk;
  gemm_core8_nt(Ab, Mk, Bb, Mk, Mk, ldsA, ldsB, acc);

  EPILOGUE_VARS
  const int rowbase = b * Nq + tx * 128 + wm * 64;
#pragma unroll
  for (int i = 0; i < 4; i++) {
    float rinv[4];
#pragma unroll
    for (int r = 0; r < 4; r++)
      rinv[r] = 1.f / rowsum[rowbase + i * 16 + r4 + r];
#pragma unroll
    for (int j = 0; j < 2; j++) {
      int gc = ty * 128 + wn * 32 + j * 16 + cn;
#pragma unroll
      for (int r = 0; r < 4; r++) {
        int gr = tx * 128 + wm * 64 + i * 16 + r4 + r;
        ctx[((size_t)b * Nq + gr) * 512 + gc] = f2bf(acc[i][j][r] * rinv[r]);
      }
    }
  }
}

// ---------------------------------------------------------------------------
// Small utility kernels
// ---------------------------------------------------------------------------
// transpose + concat weights -> bf16; concat biases; zero dsum
__global__ void k_prep_w(
    const float* __restrict__ Wqs, const float* __restrict__ Wqe,
    const float* __restrict__ Wks, const float* __restrict__ Wvs,
    const float* __restrict__ Wke, const float* __restrict__ Wve,
    const float* __restrict__ W1,  const float* __restrict__ W2,
    const float* __restrict__ bqs, const float* __restrict__ bqe,
    const float* __restrict__ bks, const float* __restrict__ bvs,
    const float* __restrict__ bke, const float* __restrict__ bve,
    unsigned short* __restrict__ WqT, unsigned short* __restrict__ WkT,
    unsigned short* __restrict__ W1T, unsigned short* __restrict__ W2T,
    float* __restrict__ bq, float* __restrict__ bk, float* __restrict__ dsum)
{
  int gid = blockIdx.x * 256 + threadIdx.x;
  int idx = gid;
  if (idx < 512 * 512) {                       // WqT[j,k], j: qs|qe
    int j = idx >> 9, k = idx & 511;
    float v = (j < 256) ? Wqs[k * 256 + j] : Wqe[k * 256 + (j - 256)];
    WqT[idx] = f2bf(v);
  } else if ((idx -= 512 * 512) < 1024 * 512) { // WkT[j,k], j: ks|vs|ke|ve
    int j = idx >> 9, k = idx & 511;
    int s = j >> 8, jj = j & 255;
    const float* Wp = (s == 0) ? Wks : (s == 1) ? Wvs : (s == 2) ? Wke : Wve;
    WkT[idx] = f2bf(Wp[k * 256 + jj]);
  } else if ((idx -= 1024 * 512) < 256 * 1024) { // W1T[j,k]
    int j = idx >> 10, k = idx & 1023;
    W1T[idx] = f2bf(W1[k * 256 + j]);
  } else if ((idx -= 256 * 1024) < 256 * 256) {  // W2T[j,k]
    int j = idx >> 8, k = idx & 255;
    W2T[idx] = f2bf(W2[k * 256 + j]);
  }
  if (gid < 512)  bq[gid] = (gid < 256) ? bqs[gid] : bqe[gid - 256];
  if (gid < 1024) bk[gid] = (gid < 256) ? bks[gid]
                    : (gid < 512) ? bvs[gid - 256]
                    : (gid < 768) ? bke[gid - 512] : bve[gid - 768];
  if (gid < 8) dsum[gid] = 0.f;
}

// row sum-of-squares over 256 bf16 columns (one wave per row)
__global__ __launch_bounds__(256) void k_rowsq(
    const unsigned short* __restrict__ X, int stride, int colOff, float* __restrict__ out)
{
  int row = blockIdx.x * 4 + (threadIdx.x >> 6);
  int lane = threadIdx.x & 63;
  const unsigned short* p = X + (size_t)row * stride + colOff + lane * 4;
  uint2 u = *(const uint2*)p;
  float a0 = bf2f((unsigned short)(u.x & 0xffff));
  float a1 = bf2f((unsigned short)(u.x >> 16));
  float a2 = bf2f((unsigned short)(u.y & 0xffff));
  float a3 = bf2f((unsigned short)(u.y >> 16));
  float s = a0 * a0 + a1 * a1 + a2 * a2 + a3 * a3;
#pragma unroll
  for (int o = 32; o; o >>= 1) s += __shfl_down(s, o);
  if (lane == 0) out[row] = s;
}

// VT[b, j, m] = Xk[b*M+m, (j<256)?256+j:512+j]  (v_struct | v_elec transposed)
__global__ void k_trans_vt(const unsigned short* __restrict__ Xk, unsigned short* __restrict__ VT) {
  __shared__ unsigned short t[32][33];
  const int b = blockIdx.z;
  const int m0 = blockIdx.x * 32, j0 = blockIdx.y * 32;
  const int tx = threadIdx.x, ty = threadIdx.y;
#pragma unroll
  for (int i = 0; i < 4; i++) {
    int m = m0 + ty + i * 8;
    int j = j0 + tx;
    int c = (j < 256) ? (256 + j) : (512 + j);
    t[ty + i * 8][tx] = Xk[((size_t)b * Mk + m) * 1024 + c];
  }
  __syncthreads();
#pragma unroll
  for (int i = 0; i < 4; i++) {
    int j = j0 + ty + i * 8;
    int m = m0 + tx;
    VT[((size_t)b * 512 + j) * Mk + m] = t[tx][ty + i * 8];
  }
}

// fused = [ctx_s | ctx_e | ctx_s-ctx_e | ctx_s*ctx_e]
__global__ void k_fused(const unsigned short* __restrict__ ctx, unsigned short* __restrict__ fused) {
  int idx = blockIdx.x * 256 + threadIdx.x;
  int bn = idx >> 8;
  int j = idx & 255;
  float cs = bf2f(ctx[(size_t)bn * 512 + j]);
  float ce = bf2f(ctx[(size_t)bn * 512 + 256 + j]);
  size_t o = (size_t)bn * 1024 + j;
  fused[o]       = f2bf(cs);
  fused[o + 256] = f2bf(ce);
  fused[o + 512] = f2bf(cs - ce);
  fused[o + 768] = f2bf(cs * ce);
}

// ---------------------------------------------------------------------------
extern "C" void kernel_launch(void* const* d_in, const int* in_sizes, int n_in,
                              void* d_out, int out_size, void* d_ws, size_t ws_size,
                              hipStream_t stream) {
  (void)in_sizes; (void)n_in; (void)out_size; (void)ws_size;
  const float* q_fp  = (const float*)d_in[0];
  const float* v_ret = (const float*)d_in[1];
  const float* pi    = (const float*)d_in[2];
  const float* Wqs = (const float*)d_in[3];  const float* bqs = (const float*)d_in[4];
  const float* Wks = (const float*)d_in[5];  const float* bks = (const float*)d_in[6];
  const float* Wvs = (const float*)d_in[7];  const float* bvs = (const float*)d_in[8];
  const float* Wqe = (const float*)d_in[9];  const float* bqe = (const float*)d_in[10];
  const float* Wke = (const float*)d_in[11]; const float* bke = (const float*)d_in[12];
  const float* Wve = (const float*)d_in[13]; const float* bve = (const float*)d_in[14];
  const float* W1  = (const float*)d_in[15]; const float* b1  = (const float*)d_in[16];
  const float* W2  = (const float*)d_in[17]; const float* b2  = (const float*)d_in[18];
  const float* gamma = (const float*)d_in[19];
  const float* ew    = (const float*)d_in[20];

  char* w = (char*)d_ws;
  unsigned short* WqT = (unsigned short*)(w + 0);          // 512x512 bf16
  unsigned short* WkT = (unsigned short*)(w + 524288);     // 1024x512
  unsigned short* W1T = (unsigned short*)(w + 1572864);    // 256x1024
  unsigned short* W2T = (unsigned short*)(w + 2097152);    // 256x256
  float* bq   = (float*)(w + 2228224);                     // 512
  float* bk   = (float*)(w + 2230272);                     // 1024
  float* q2   = (float*)(w + 2234368);                     // 16384
  float* k2   = (float*)(w + 2299904);                     // 16384
  float* dsum = (float*)(w + 2365440);                     // 8
  unsigned short* ctx  = (unsigned short*)(w + 2365696);   // 16384x512 bf16 (16.8MB)
  unsigned short* hbuf = (unsigned short*)(w + 19142912);  // 16384x256 bf16 (8.4MB)
  unsigned short* Xq = (unsigned short*)(w + 35920128);    // 16384x512 (qs|qe)
  unsigned short* Xk = (unsigned short*)(w + 52697344);    // 16384x1024 (ks|vs|ke|ve)
  unsigned short* VT = (unsigned short*)(w + 86251776);    // 8x512x2048
  unsigned short* attn = (unsigned short*)(w + 103028992); // 16384x2048 bf16 unnorm
  unsigned short* fused = attn;                            // reuse (attn dead after PV)
  // cast buffers live in the attn slot (dead until k_softmax writes it)
  unsigned short* castQ = (unsigned short*)(w + 103028992);          // 16384x512 bf16
  unsigned short* castK = (unsigned short*)(w + 103028992 + 16777216); // 16384x512 bf16
  // sd chunk buffer (2 batches = exactly 32MiB) overlays ctx+hbuf, which are
  // dead until k_fused/MLP.
  unsigned* sdbuf = (unsigned*)(w + 2365696);
  float* rowsum = (float*)d_out;  // 64KB scratch in d_out; overwritten by final GEMM

  k_prep_w<<<4352, 256, 0, stream>>>(Wqs, Wqe, Wks, Wvs, Wke, Wve, W1, W2,
                                     bqs, bqe, bks, bvs, bke, bve,
                                     WqT, WkT, W1T, W2T, bq, bk, dsum);
  // cast fp32 inputs -> bf16 once (removes in-loop VALU packing from proj)
  k_cast<<<2048, 512, 0, stream>>>(q_fp,  castQ, (16384 * 512) / 8);
  k_cast<<<2048, 512, 0, stream>>>(v_ret, castK, (16384 * 512) / 8);
  // projections on the proven pure-bf16 core: Xq=[qs|qe], Xk=[ks|vs|ke|ve]
  k_gemm_bias<0><<<dim3(128, 4), 512, 0, stream>>>(castQ, WqT, bq, Xq, 512, 512);
  k_gemm_bias<0><<<dim3(128, 8), 512, 0, stream>>>(castK, WkT, bk, Xk, 1024, 512);
  k_rowsq<<<4096, 256, 0, stream>>>(Xq, 512, 256, q2);
  k_rowsq<<<4096, 256, 0, stream>>>(Xk, 1024, 512, k2);
  // chunked (2 batches each): fused GEMMs -> packed (s,d); then streaming softmax
  for (int c = 0; c < 4; ++c) {
    k_sd<<<dim3(16, 16, 2), 512, 0, stream>>>(Xq, Xk, q2, k2, 2 * c, dsum, sdbuf);
    k_softmax<<<1024, 256, 0, stream>>>(sdbuf, pi, dsum, gamma, ew, 2 * c,
                                        attn, rowsum);
  }
  // transpose v_struct/v_elec -> VT
  k_trans_vt<<<dim3(64, 16, 8), dim3(32, 8), 0, stream>>>(Xk, VT);
  // ctx = (attn @ [Vs|Ve]) / rowsum
  k_pv<<<dim3(64, 1, 8), 512, 0, stream>>>(attn, VT, rowsum, ctx);
  // fused features
  k_fused<<<16384, 256, 0, stream>>>(ctx, fused);
  // MLP: h = silu(fused @ W1 + b1); out = h @ W2 + b2 (fp32)
  k_gemm_bias<1><<<dim3(128, 2), 512, 0, stream>>>(fused, W1T, b1, hbuf, 256, 1024);
  k_gemm_bias<2><<<dim3(128, 2), 512, 0, stream>>>(hbuf, W2T, b2, d_out, 256, 256);
}

// Round 9
// 550.785 us; speedup vs baseline: 1.4278x; 1.0156x over previous
//
#include <hip/hip_runtime.h>

// PGWCrossAttention on MI355X (gfx950), bf16 MFMA pipeline.
// R13: pass-elimination harvest (the only lever that has paid: R6, R12).
//  - k_rowsq x2 folded into k_proj_sq epilogue (squares the bf16-ROUNDED
//    value -> bit-compat q2/k2; shfl-reduce over cn; atomicAdd per row).
//  - k_fused folded into k_pv: B-tile = paired struct/elec V-rows (waves 0-3
//    stage struct, 4-7 elec via per-wave-adjusted B pointer into the SAME
//    core), LDS pair-exchange (32KB, reuses GEMM LDS), writes
//    [cs|ce|cs-ce|cs*ce] directly. ctx buffer gone.
//  - k_cast x2 merged into one launch.
// 18 -> 14 dispatches, ~85 MB less traffic. GEMM cores untouched (proven).
#define Bsz 8
#define Nq  2048
#define Mk  2048
#define BKt 32          // K-tile per MFMA step
#define BUFE (128 * BKt) // elements per LDS buffer

typedef __attribute__((ext_vector_type(8))) short   short8;   // 8 bf16 (4 VGPRs)
typedef __attribute__((ext_vector_type(4))) float   floatx4;  // MFMA acc

__device__ __forceinline__ unsigned short f2bf(float f) {
  union { float f; unsigned u; } x; x.f = f;
  unsigned r = x.u + 0x7fffu + ((x.u >> 16) & 1u);   // RNE
  return (unsigned short)(r >> 16);
}
__device__ __forceinline__ float bf2f(unsigned short s) {
  union { unsigned u; float f; } x; x.u = ((unsigned)s) << 16;
  return x.f;
}

// async global->LDS, 16B per lane. LDS dest is wave-uniform base + lane*16.
__device__ __forceinline__ void gload16(const unsigned short* g, unsigned short* l) {
  __builtin_amdgcn_global_load_lds(
      (const __attribute__((address_space(1))) void*)g,
      (__attribute__((address_space(3))) void*)l, 16, 0, 0);
}

// ---------------------------------------------------------------------------
// 8-wave NT GEMM core 128x128, double-buffered: C += A[128,K] . B[128,K]^T.
// 512 threads, waves 2x4, wave tile 64x32, acc[4][2]. B may be a per-wave-
// adjusted pointer (wave w only touches rows [16w,16w+16)).
// ---------------------------------------------------------------------------
__device__ __forceinline__ void gemm_core8_nt(
    const unsigned short* __restrict__ A, int lda,
    const unsigned short* __restrict__ B, int ldb,
    int K, unsigned short* ldsA, unsigned short* ldsB,
    floatx4 (&acc)[4][2])
{
  const int tid  = threadIdx.x;
  const int lane = tid & 63;
  const int wid  = tid >> 6;          // 0..7
  const int wm   = wid & 1;
  const int wn   = wid >> 1;          // 0..3
  const int fr   = lane & 15;
  const int fk   = (lane >> 4) << 3;
  const int lr   = lane >> 2;         // 0..15
  const int lc   = (lane & 3) << 3;   // 0/8/16/24
  const int r0   = wid << 4;          // 16 rows per wave

  const unsigned short* gA = A + (size_t)(r0 + lr) * lda + lc;
  const unsigned short* gB = B + (size_t)(r0 + lr) * ldb + lc;
  unsigned short* lA = ldsA + r0 * BKt;
  unsigned short* lB = ldsB + r0 * BKt;
  const unsigned short* fa = ldsA + (wm * 64 + fr) * BKt + fk;
  const unsigned short* fb = ldsB + (wn * 32 + fr) * BKt + fk;

  // prologue: stage K-step 0 into buffer 0
  gload16(gA, lA); gA += BKt;
  gload16(gB, lB); gB += BKt;
  __syncthreads();

  int cur = 0;
  for (int k0 = 0; k0 < K; k0 += BKt) {
    const int nxt = cur ^ 1;
    if (k0 + BKt < K) {               // issue next-tile prefetch (async)
      gload16(gA, lA + nxt * BUFE); gA += BKt;
      gload16(gB, lB + nxt * BUFE); gB += BKt;
    }
    const unsigned short* fac = fa + cur * BUFE;
    const unsigned short* fbc = fb + cur * BUFE;
    short8 af[4], bfr[2];
#pragma unroll
    for (int i = 0; i < 4; i++) af[i]  = *(const short8*)(fac + i * 16 * BKt);
#pragma unroll
    for (int j = 0; j < 2; j++) bfr[j] = *(const short8*)(fbc + j * 16 * BKt);
#pragma unroll
    for (int i = 0; i < 4; i++)
#pragma unroll
      for (int j = 0; j < 2; j++)
        acc[i][j] = __builtin_amdgcn_mfma_f32_16x16x32_bf16(af[i], bfr[j], acc[i][j], 0, 0, 0);
    __syncthreads();                  // drains prefetch; buf safe to overwrite
    cur = nxt;
  }
}

#define EPILOGUE_VARS \
  const int lane = threadIdx.x & 63; \
  const int wid  = threadIdx.x >> 6; \
  const int wm   = wid & 1; \
  const int wn   = wid >> 1; \
  const int r4   = (lane >> 4) * 4;  \
  const int cn   = lane & 15; \
  (void)wid;

// ---------------------------------------------------------------------------
// GEMM + bias (bf16 A), 8-wave dbuf. MODE 1: silu -> bf16. MODE 2: store fp32.
// ---------------------------------------------------------------------------
template<int MODE>
__global__ __launch_bounds__(512, 4) void k_gemm_bias(
    const unsigned short* __restrict__ A, const unsigned short* __restrict__ Bw,
    const float* __restrict__ bias, void* __restrict__ Cout, int Ncols, int K)
{
  __shared__ alignas(16) unsigned short ldsA[2 * BUFE];
  __shared__ alignas(16) unsigned short ldsB[2 * BUFE];
  floatx4 acc[4][2];
#pragma unroll
  for (int i = 0; i < 4; i++)
#pragma unroll
    for (int j = 0; j < 2; j++)
#pragma unroll
      for (int t = 0; t < 4; t++) acc[i][j][t] = 0.f;

  const unsigned short* Ab = A + (size_t)blockIdx.x * 128 * K;
  const unsigned short* Bb = Bw + (size_t)blockIdx.y * 128 * K;
  gemm_core8_nt(Ab, K, Bb, K, K, ldsA, ldsB, acc);

  EPILOGUE_VARS
#pragma unroll
  for (int i = 0; i < 4; i++) {
#pragma unroll
    for (int j = 0; j < 2; j++) {
      int gc = blockIdx.y * 128 + wn * 32 + j * 16 + cn;
      float bv = bias[gc];
#pragma unroll
      for (int r = 0; r < 4; r++) {
        int gr = blockIdx.x * 128 + wm * 64 + i * 16 + r4 + r;
        float v = acc[i][j][r] + bv;
        if constexpr (MODE == 1) v = v / (1.f + __expf(-v));
        if constexpr (MODE == 2)
          ((float*)Cout)[(size_t)gr * Ncols + gc] = v;
        else
          ((unsigned short*)Cout)[(size_t)gr * Ncols + gc] = f2bf(v);
      }
    }
  }
}

// ---------------------------------------------------------------------------
// Projection GEMM + fused row-sum-of-squares over the elec 256-col window.
// Squares the bf16-ROUNDED stored value -> q2/k2 bit-compat with old k_rowsq.
// Window is 256 cols = 2 aligned y-blocks -> insq is block-uniform.
// ---------------------------------------------------------------------------
__global__ __launch_bounds__(512, 4) void k_proj_sq(
    const unsigned short* __restrict__ A, const unsigned short* __restrict__ Bw,
    const float* __restrict__ bias, unsigned short* __restrict__ Cout,
    int Ncols, int K, float* __restrict__ sq, int elecOff)
{
  __shared__ alignas(16) unsigned short ldsA[2 * BUFE];
  __shared__ alignas(16) unsigned short ldsB[2 * BUFE];
  floatx4 acc[4][2];
#pragma unroll
  for (int i = 0; i < 4; i++)
#pragma unroll
    for (int j = 0; j < 2; j++)
#pragma unroll
      for (int t = 0; t < 4; t++) acc[i][j][t] = 0.f;

  const unsigned short* Ab = A + (size_t)blockIdx.x * 128 * K;
  const unsigned short* Bb = Bw + (size_t)blockIdx.y * 128 * K;
  gemm_core8_nt(Ab, K, Bb, K, K, ldsA, ldsB, acc);

  EPILOGUE_VARS
  const int c0 = blockIdx.y * 128;
  const bool insq = (c0 >= elecOff) && (c0 < elecOff + 256);
#pragma unroll
  for (int i = 0; i < 4; i++) {
    float s4[4] = {0.f, 0.f, 0.f, 0.f};
#pragma unroll
    for (int j = 0; j < 2; j++) {
      int gc = c0 + wn * 32 + j * 16 + cn;
      float bv = bias[gc];
#pragma unroll
      for (int r = 0; r < 4; r++) {
        int gr = blockIdx.x * 128 + wm * 64 + i * 16 + r4 + r;
        float v = acc[i][j][r] + bv;
        unsigned short us = f2bf(v);
        Cout[(size_t)gr * Ncols + gc] = us;
        if (insq) { float vr = bf2f(us); s4[r] += vr * vr; }
      }
    }
    if (insq) {
#pragma unroll
      for (int r = 0; r < 4; r++) {
        s4[r] += __shfl_xor(s4[r], 1);
        s4[r] += __shfl_xor(s4[r], 2);
        s4[r] += __shfl_xor(s4[r], 4);
        s4[r] += __shfl_xor(s4[r], 8);
      }
      if (cn == 0) {
#pragma unroll
        for (int r = 0; r < 4; r++)
          atomicAdd(sq + blockIdx.x * 128 + wm * 64 + i * 16 + r4 + r, s4[r]);
      }
    }
  }
}

// ---------------------------------------------------------------------------
// k_cast2: fp32 -> bf16 streaming for both inputs in one launch.
// ---------------------------------------------------------------------------
__global__ __launch_bounds__(512) void k_cast2(
    const float* __restrict__ a, const float* __restrict__ b,
    unsigned short* __restrict__ da, unsigned short* __restrict__ db, int n8each)
{
  const int total = 2 * n8each;
  for (int i = blockIdx.x * 512 + threadIdx.x; i < total; i += gridDim.x * 512) {
    const float* s; unsigned short* d; int k;
    if (i < n8each) { s = a; d = da; k = i; }
    else            { s = b; d = db; k = i - n8each; }
    const float4 f0 = *(const float4*)(s + (size_t)k * 8);
    const float4 f1 = *(const float4*)(s + (size_t)k * 8 + 4);
    uint4 p;
    p.x = f2bf(f0.x) | ((unsigned)f2bf(f0.y) << 16);
    p.y = f2bf(f0.z) | ((unsigned)f2bf(f0.w) << 16);
    p.z = f2bf(f1.x) | ((unsigned)f2bf(f1.y) << 16);
    p.w = f2bf(f1.z) | ((unsigned)f2bf(f1.w) << 16);
    *(uint4*)(d + (size_t)k * 8) = p;
  }
}

// ---------------------------------------------------------------------------
// k_sd: FUSED struct+elec GEMMs, one interleaved 8-wave core. Per K-step:
// stage 4 slices (As,Ae,Bs,Be) + 16 MFMA. Writes packed uint32
// (bf16 s/16 | bf16 d), accumulates dsum[b]. Chunk = 2 batches (z=0/1).
// ---------------------------------------------------------------------------
__global__ __launch_bounds__(512, 4) void k_sd(
    const unsigned short* __restrict__ Xq, const unsigned short* __restrict__ Xk,
    const float* __restrict__ q2, const float* __restrict__ k2,
    int b0, float* __restrict__ dsum, unsigned* __restrict__ sd)
{
  __shared__ alignas(16) unsigned short ldsAs[2 * BUFE];
  __shared__ alignas(16) unsigned short ldsAe[2 * BUFE];
  __shared__ alignas(16) unsigned short ldsBs[2 * BUFE];
  __shared__ alignas(16) unsigned short ldsBe[2 * BUFE];
  floatx4 accS[4][2], accE[4][2];
#pragma unroll
  for (int i = 0; i < 4; i++)
#pragma unroll
    for (int j = 0; j < 2; j++)
#pragma unroll
      for (int t = 0; t < 4; t++) { accS[i][j][t] = 0.f; accE[i][j][t] = 0.f; }

  const int z = blockIdx.z;           // chunk-local batch 0/1
  const int b = b0 + z;

  const int tid  = threadIdx.x;
  const int lane = tid & 63;
  const int wid  = tid >> 6;
  const int wm   = wid & 1;
  const int wn   = wid >> 1;
  const int fr   = lane & 15;
  const int fk   = (lane >> 4) << 3;
  const int lr   = lane >> 2;
  const int lc   = (lane & 3) << 3;
  const int r0   = wid << 4;

  const unsigned short* gAs = Xq + ((size_t)(b * Nq) + blockIdx.x * 128 + r0 + lr) * 512 + lc;
  const unsigned short* gAe = gAs + 256;
  const unsigned short* gBs = Xk + ((size_t)(b * Mk) + blockIdx.y * 128 + r0 + lr) * 1024 + lc;
  const unsigned short* gBe = gBs + 512;
  unsigned short* lAs = ldsAs + r0 * BKt;
  unsigned short* lAe = ldsAe + r0 * BKt;
  unsigned short* lBs = ldsBs + r0 * BKt;
  unsigned short* lBe = ldsBe + r0 * BKt;
  const unsigned short* fas = ldsAs + (wm * 64 + fr) * BKt + fk;
  const unsigned short* fae = ldsAe + (wm * 64 + fr) * BKt + fk;
  const unsigned short* fbs = ldsBs + (wn * 32 + fr) * BKt + fk;
  const unsigned short* fbe = ldsBe + (wn * 32 + fr) * BKt + fk;

  // prologue: stage K-step 0 into buffer 0
  gload16(gAs, lAs); gAs += BKt;
  gload16(gAe, lAe); gAe += BKt;
  gload16(gBs, lBs); gBs += BKt;
  gload16(gBe, lBe); gBe += BKt;
  __syncthreads();

  int cur = 0;
  for (int k0 = 0; k0 < 256; k0 += BKt) {
    const int nxt = cur ^ 1;
    if (k0 + BKt < 256) {
      gload16(gAs, lAs + nxt * BUFE); gAs += BKt;
      gload16(gAe, lAe + nxt * BUFE); gAe += BKt;
      gload16(gBs, lBs + nxt * BUFE); gBs += BKt;
      gload16(gBe, lBe + nxt * BUFE); gBe += BKt;
    }
    {   // struct 8 MFMA
      short8 af[4], bfr[2];
      const unsigned short* fac = fas + cur * BUFE;
      const unsigned short* fbc = fbs + cur * BUFE;
#pragma unroll
      for (int i = 0; i < 4; i++) af[i]  = *(const short8*)(fac + i * 16 * BKt);
#pragma unroll
      for (int j = 0; j < 2; j++) bfr[j] = *(const short8*)(fbc + j * 16 * BKt);
#pragma unroll
      for (int i = 0; i < 4; i++)
#pragma unroll
        for (int j = 0; j < 2; j++)
          accS[i][j] = __builtin_amdgcn_mfma_f32_16x16x32_bf16(af[i], bfr[j], accS[i][j], 0, 0, 0);
    }
    {   // elec 8 MFMA
      short8 af[4], bfr[2];
      const unsigned short* fac = fae + cur * BUFE;
      const unsigned short* fbc = fbe + cur * BUFE;
#pragma unroll
      for (int i = 0; i < 4; i++) af[i]  = *(const short8*)(fac + i * 16 * BKt);
#pragma unroll
      for (int j = 0; j < 2; j++) bfr[j] = *(const short8*)(fbc + j * 16 * BKt);
#pragma unroll
      for (int i = 0; i < 4; i++)
#pragma unroll
        for (int j = 0; j < 2; j++)
          accE[i][j] = __builtin_amdgcn_mfma_f32_16x16x32_bf16(af[i], bfr[j], accE[i][j], 0, 0, 0);
    }
    __syncthreads();
    cur = nxt;
  }

  const int r4 = (lane >> 4) * 4;
  const int cn = lane & 15;
  const int colT = blockIdx.y * 128 + wn * 32;
  const float kk0 = k2[b * Mk + colT + cn];
  const float kk1 = k2[b * Mk + colT + 16 + cn];

  float lsum = 0.f;
#pragma unroll
  for (int i = 0; i < 4; i++) {
#pragma unroll
    for (int r = 0; r < 4; r++) {
      const int n = blockIdx.x * 128 + wm * 64 + i * 16 + r4 + r;
      const float qq = q2[b * Nq + n];
      unsigned* srow = sd + (size_t)(z * Nq + n) * Mk;
#pragma unroll
      for (int j = 0; j < 2; j++) {
        const int m = colT + j * 16 + cn;
        float d = sqrtf(fmaxf(qq + (j ? kk1 : kk0) - 2.f * accE[i][j][r], 1e-12f));
        lsum += d;
        srow[m] = (unsigned)f2bf(accS[i][j][r] * 0.0625f)
                | ((unsigned)f2bf(d) << 16);
      }
    }
  }
#pragma unroll
  for (int o = 32; o; o >>= 1) lsum += __shfl_down(lsum, o);
  __syncthreads();                    // LDS frag reads done before reuse
  float* red = (float*)ldsAs;
  if (lane == 0) red[wid] = lsum;
  __syncthreads();
  if (threadIdx.x == 0) {
    float s = 0.f;
#pragma unroll
    for (int t = 0; t < 8; t++) s += red[t];
    atomicAdd(dsum + b, s);
  }
}

// ---------------------------------------------------------------------------
// k_softmax: streaming. One wave per row: e = exp(s - ew*d/scale) * pi^gamma,
// attn (bf16 unnorm) + rowsum[row] (direct store, no atomics). Fully coalesced.
// ---------------------------------------------------------------------------
__global__ __launch_bounds__(256) void k_softmax(
    const unsigned* __restrict__ sd, const float* __restrict__ pi,
    const float* __restrict__ dsum, const float* __restrict__ gamma_p,
    const float* __restrict__ ew_p, int b0,
    unsigned short* __restrict__ attn, float* __restrict__ rowsum)
{
  const int wid  = threadIdx.x >> 6;
  const int lane = threadIdx.x & 63;
  const int rl   = blockIdx.x * 4 + wid;     // chunk-local row 0..4095
  const int b    = b0 + (rl >> 11);
  const int n    = rl & 2047;

  const float scale = fmaxf(dsum[b] * (1.f / (2048.f * 2048.f)), 1e-4f);
  const float einv  = ew_p[0] / scale;
  const float gv    = gamma_p[0];
  const bool  g1    = (gv == 1.0f);          // wave-uniform fast path

  const unsigned*  sp = sd  + (size_t)rl * Mk;
  const float*     pp = pi  + ((size_t)b * Nq + n) * Mk;
  unsigned short*  ap = attn + ((size_t)b * Nq + n) * Mk;

  float rs = 0.f;
  for (int it = 0; it < 8; ++it) {
    const int c = it * 256 + lane * 4;
    const uint4  sv = *(const uint4*)(sp + c);
    const float4 pv = *(const float4*)(pp + c);
    const unsigned uu[4]  = {sv.x, sv.y, sv.z, sv.w};
    const float    pp4[4] = {pv.x, pv.y, pv.z, pv.w};
    float e[4];
#pragma unroll
    for (int t = 0; t < 4; ++t) {
      union { unsigned u; float f; } cs, cd;
      cs.u = uu[t] << 16;                    // s * 0.0625
      cd.u = uu[t] & 0xffff0000u;            // d
      float p  = fmaxf(pp4[t], 1e-9f);
      float pf = g1 ? p : __expf(gv * __logf(p));
      e[t] = __expf(cs.f - einv * cd.f) * pf;
      rs += e[t];
    }
    uint2 st;
    st.x = (unsigned)f2bf(e[0]) | ((unsigned)f2bf(e[1]) << 16);
    st.y = (unsigned)f2bf(e[2]) | ((unsigned)f2bf(e[3]) << 16);
    *(uint2*)(ap + c) = st;
  }
#pragma unroll
  for (int o = 32; o; o >>= 1) rs += __shfl_down(rs, o);
  if (lane == 0) rowsum[b * Nq + n] = rs;
}

// ---------------------------------------------------------------------------
// PV + feature-concat: each block computes paired struct/elec cols.
// B-tile: LDS rows 0..63 = V-struct cols [ty*64,+64), rows 64..127 = V-elec
// cols [256+ty*64,+64) (waves 4-7 get an adjusted B pointer). Epilogue
// exchanges (cs,ce) pairs via a 32KB LDS tile (reuses GEMM LDS) and writes
// fused = [cs|ce|cs-ce|cs*ce] directly. XCD swizzle on (tx,ty) as before.
// ---------------------------------------------------------------------------
__global__ __launch_bounds__(512, 4) void k_pv(
    const unsigned short* __restrict__ At, const unsigned short* __restrict__ VT,
    const float* __restrict__ rowsum, unsigned short* __restrict__ fused)
{
  __shared__ alignas(16) unsigned short smem[4 * BUFE];   // 64KB: A dbuf | B dbuf
  unsigned short* ldsA = smem;
  unsigned short* ldsB = smem + 2 * BUFE;
  floatx4 acc[4][2];
#pragma unroll
  for (int i = 0; i < 4; i++)
#pragma unroll
    for (int j = 0; j < 2; j++)
#pragma unroll
      for (int t = 0; t < 4; t++) acc[i][j][t] = 0.f;

  const int l  = blockIdx.x;            // 0..63
  const int lg = ((l & 7) << 3) | (l >> 3);
  const int tx = lg >> 2;               // row tile 0..15
  const int ty = lg & 3;                // col-pair tile 0..3
  const int b  = blockIdx.z;
  const unsigned short* Ab  = At + ((size_t)b * Nq + tx * 128) * (size_t)Mk;
  const unsigned short* Bb0 = VT + ((size_t)b * 512 + ty * 64) * (size_t)Mk;        // struct
  const unsigned short* Bb1 = VT + ((size_t)b * 512 + 256 + ty * 64) * (size_t)Mk;  // elec
  // per-wave-adjusted B base: waves 0-3 stage struct rows, 4-7 elec rows
  const int wid0 = threadIdx.x >> 6;
  const unsigned short* Beff = (wid0 < 4) ? Bb0 : (Bb1 - (size_t)64 * Mk);
  gemm_core8_nt(Ab, Mk, Beff, Mk, Mk, ldsA, ldsB, acc);

  EPILOGUE_VARS
  const int rowbase = b * Nq + tx * 128 + wm * 64;
  // stage normalized bf16 into [128][128] ctile (32KB, reuses GEMM LDS;
  // safe: core's final __syncthreads already passed)
  unsigned short (*ctile)[128] = (unsigned short(*)[128])smem;
#pragma unroll
  for (int i = 0; i < 4; i++) {
    float rinv[4];
#pragma unroll
    for (int r = 0; r < 4; r++)
      rinv[r] = 1.f / rowsum[rowbase + i * 16 + r4 + r];
#pragma unroll
    for (int j = 0; j < 2; j++) {
      const int lc2 = wn * 32 + j * 16 + cn;   // 0..63 struct, 64..127 elec
#pragma unroll
      for (int r = 0; r < 4; r++)
        ctile[wm * 64 + i * 16 + r4 + r][lc2] = f2bf(acc[i][j][r] * rinv[r]);
    }
  }
  __syncthreads();
  // pair-exchange write: fused[row] = [cs | ce | cs-ce | cs*ce]
  const int tid = threadIdx.x;
  for (int p = tid; p < 128 * 64; p += 512) {
    const int row = p >> 6;
    const int c   = p & 63;
    const unsigned short us = ctile[row][c];
    const unsigned short ue = ctile[row][64 + c];
    const float cs = bf2f(us);
    const float ce = bf2f(ue);
    unsigned short* out = fused + ((size_t)(b * Nq) + tx * 128 + row) * 1024 + ty * 64 + c;
    out[0]   = us;
    out[256] = ue;
    out[512] = f2bf(cs - ce);
    out[768] = f2bf(cs * ce);
  }
}

// ---------------------------------------------------------------------------
// Small utility kernels
// ---------------------------------------------------------------------------
// transpose + concat weights -> bf16; concat biases; zero dsum/q2/k2
__global__ void k_prep_w(
    const float* __restrict__ Wqs, const float* __restrict__ Wqe,
    const float* __restrict__ Wks, const float* __restrict__ Wvs,
    const float* __restrict__ Wke, const float* __restrict__ Wve,
    const float* __restrict__ W1,  const float* __restrict__ W2,
    const float* __restrict__ bqs, const float* __restrict__ bqe,
    const float* __restrict__ bks, const float* __restrict__ bvs,
    const float* __restrict__ bke, const float* __restrict__ bve,
    unsigned short* __restrict__ WqT, unsigned short* __restrict__ WkT,
    unsigned short* __restrict__ W1T, unsigned short* __restrict__ W2T,
    float* __restrict__ bq, float* __restrict__ bk, float* __restrict__ dsum,
    float* __restrict__ q2z, float* __restrict__ k2z)
{
  int gid = blockIdx.x * 256 + threadIdx.x;
  int idx = gid;
  if (idx < 512 * 512) {                       // WqT[j,k], j: qs|qe
    int j = idx >> 9, k = idx & 511;
    float v = (j < 256) ? Wqs[k * 256 + j] : Wqe[k * 256 + (j - 256)];
    WqT[idx] = f2bf(v);
  } else if ((idx -= 512 * 512) < 1024 * 512) { // WkT[j,k], j: ks|vs|ke|ve
    int j = idx >> 9, k = idx & 511;
    int s = j >> 8, jj = j & 255;
    const float* Wp = (s == 0) ? Wks : (s == 1) ? Wvs : (s == 2) ? Wke : Wve;
    WkT[idx] = f2bf(Wp[k * 256 + jj]);
  } else if ((idx -= 1024 * 512) < 256 * 1024) { // W1T[j,k]
    int j = idx >> 10, k = idx & 1023;
    W1T[idx] = f2bf(W1[k * 256 + j]);
  } else if ((idx -= 256 * 1024) < 256 * 256) {  // W2T[j,k]
    int j = idx >> 8, k = idx & 255;
    W2T[idx] = f2bf(W2[k * 256 + j]);
  }
  if (gid < 512)  bq[gid] = (gid < 256) ? bqs[gid] : bqe[gid - 256];
  if (gid < 1024) bk[gid] = (gid < 256) ? bks[gid]
                    : (gid < 512) ? bvs[gid - 256]
                    : (gid < 768) ? bke[gid - 512] : bve[gid - 768];
  if (gid < 8) dsum[gid] = 0.f;
  if (gid < 16384) q2z[gid] = 0.f;
  else if (gid < 32768) k2z[gid - 16384] = 0.f;
}

// VT[b, j, m] = Xk[b*M+m, (j<256)?256+j:512+j]  (v_struct | v_elec transposed)
__global__ void k_trans_vt(const unsigned short* __restrict__ Xk, unsigned short* __restrict__ VT) {
  __shared__ unsigned short t[32][33];
  const int b = blockIdx.z;
  const int m0 = blockIdx.x * 32, j0 = blockIdx.y * 32;
  const int tx = threadIdx.x, ty = threadIdx.y;
#pragma unroll
  for (int i = 0; i < 4; i++) {
    int m = m0 + ty + i * 8;
    int j = j0 + tx;
    int c = (j < 256) ? (256 + j) : (512 + j);
    t[ty + i * 8][tx] = Xk[((size_t)b * Mk + m) * 1024 + c];
  }
  __syncthreads();
#pragma unroll
  for (int i = 0; i < 4; i++) {
    int j = j0 + ty + i * 8;
    int m = m0 + tx;
    VT[((size_t)b * 512 + j) * Mk + m] = t[tx][ty + i * 8];
  }
}

// ---------------------------------------------------------------------------
extern "C" void kernel_launch(void* const* d_in, const int* in_sizes, int n_in,
                              void* d_out, int out_size, void* d_ws, size_t ws_size,
                              hipStream_t stream) {
  (void)in_sizes; (void)n_in; (void)out_size; (void)ws_size;
  const float* q_fp  = (const float*)d_in[0];
  const float* v_ret = (const float*)d_in[1];
  const float* pi    = (const float*)d_in[2];
  const float* Wqs = (const float*)d_in[3];  const float* bqs = (const float*)d_in[4];
  const float* Wks = (const float*)d_in[5];  const float* bks = (const float*)d_in[6];
  const float* Wvs = (const float*)d_in[7];  const float* bvs = (const float*)d_in[8];
  const float* Wqe = (const float*)d_in[9];  const float* bqe = (const float*)d_in[10];
  const float* Wke = (const float*)d_in[11]; const float* bke = (const float*)d_in[12];
  const float* Wve = (const float*)d_in[13]; const float* bve = (const float*)d_in[14];
  const float* W1  = (const float*)d_in[15]; const float* b1  = (const float*)d_in[16];
  const float* W2  = (const float*)d_in[17]; const float* b2  = (const float*)d_in[18];
  const float* gamma = (const float*)d_in[19];
  const float* ew    = (const float*)d_in[20];

  char* w = (char*)d_ws;
  unsigned short* WqT = (unsigned short*)(w + 0);          // 512x512 bf16
  unsigned short* WkT = (unsigned short*)(w + 524288);     // 1024x512
  unsigned short* W1T = (unsigned short*)(w + 1572864);    // 256x1024
  unsigned short* W2T = (unsigned short*)(w + 2097152);    // 256x256
  float* bq   = (float*)(w + 2228224);                     // 512
  float* bk   = (float*)(w + 2230272);                     // 1024
  float* q2   = (float*)(w + 2234368);                     // 16384
  float* k2   = (float*)(w + 2299904);                     // 16384
  float* dsum = (float*)(w + 2365440);                     // 8
  // region 2365696..35920128 (33.5MB): sdbuf during chunk loop, then fused
  unsigned* sdbuf = (unsigned*)(w + 2365696);              // 2 batches u32
  unsigned short* fused = (unsigned short*)(w + 2365696);  // 16384x1024 bf16
  unsigned short* Xq = (unsigned short*)(w + 35920128);    // 16384x512 (qs|qe)
  unsigned short* Xk = (unsigned short*)(w + 52697344);    // 16384x1024 (ks|vs|ke|ve)
  unsigned short* VT = (unsigned short*)(w + 86251776);    // 8x512x2048 -> ends 103028992
  // region 103028992.. : castQ/castK (dead after proj) -> attn -> hbuf
  unsigned short* castQ = (unsigned short*)(w + 103028992);            // 16.8MB
  unsigned short* castK = (unsigned short*)(w + 103028992 + 16777216); // 16.8MB
  unsigned short* attn  = (unsigned short*)(w + 103028992);            // 67MB unnorm
  unsigned short* hbuf  = (unsigned short*)(w + 103028992);            // 8.4MB (attn dead)
  float* rowsum = (float*)d_out;  // 64KB scratch in d_out; overwritten by final GEMM

  k_prep_w<<<4352, 256, 0, stream>>>(Wqs, Wqe, Wks, Wvs, Wke, Wve, W1, W2,
                                     bqs, bqe, bks, bvs, bke, bve,
                                     WqT, WkT, W1T, W2T, bq, bk, dsum, q2, k2);
  // cast fp32 inputs -> bf16 once (both arrays, one launch)
  k_cast2<<<2048, 512, 0, stream>>>(q_fp, v_ret, castQ, castK, (16384 * 512) / 8);
  // projections + fused row-sum-of-squares (q2/k2 via atomics)
  k_proj_sq<<<dim3(128, 4), 512, 0, stream>>>(castQ, WqT, bq, Xq, 512, 512, q2, 256);
  k_proj_sq<<<dim3(128, 8), 512, 0, stream>>>(castK, WkT, bk, Xk, 1024, 512, k2, 512);
  // chunked (2 batches each): fused GEMMs -> packed (s,d); then streaming softmax
  for (int c = 0; c < 4; ++c) {
    k_sd<<<dim3(16, 16, 2), 512, 0, stream>>>(Xq, Xk, q2, k2, 2 * c, dsum, sdbuf);
    k_softmax<<<1024, 256, 0, stream>>>(sdbuf, pi, dsum, gamma, ew, 2 * c,
                                        attn, rowsum);
  }
  // transpose v_struct/v_elec -> VT
  k_trans_vt<<<dim3(64, 16, 8), dim3(32, 8), 0, stream>>>(Xk, VT);
  // PV + concat: fused = [ctx_s | ctx_e | ctx_s-ctx_e | ctx_s*ctx_e]
  k_pv<<<dim3(64, 1, 8), 512, 0, stream>>>(attn, VT, rowsum, fused);
  // MLP: h = silu(fused @ W1 + b1); out = h @ W2 + b2 (fp32)
  k_gemm_bias<1><<<dim3(128, 2), 512, 0, stream>>>(fused, W1T, b1, hbuf, 256, 1024);
  k_gemm_bias<2><<<dim3(128, 2), 512, 0, stream>>>(hbuf, W2T, b2, d_out, 256, 256);
}